// Round 15
// baseline (190.773 us; speedup 1.0000x reference)
//
#include <hip/hip_runtime.h>

typedef unsigned short u16;
typedef unsigned int u32;
typedef __attribute__((ext_vector_type(8))) short short8v;
typedef __attribute__((ext_vector_type(4))) float f32x4;

#define DIM 2048
#define HQN 32
#define HKVN 8
#define HD 64
#define BB 2
#define SS 2048
#define MTOT (BB*SS)
#define NKV (HKVN*HD)
#define QSCL 0.18033688011112042f   // log2(e)/8, folded into Qp

__device__ __forceinline__ u16 f2bf(float f){
  u32 u = __float_as_uint(f);
  u += 0x7FFFu + ((u >> 16) & 1u);
  return (u16)(u >> 16);
}

__device__ __forceinline__ u32 cvtpk(float a, float b){
  u32 r; asm("v_cvt_pk_bf16_f32 %0, %1, %2" : "=v"(r) : "v"(a), "v"(b)); return r;
}

__device__ __forceinline__ void gload_lds16(const void* g, void* l){
  __builtin_amdgcn_global_load_lds((const __attribute__((address_space(1))) u32*)g,
                                   (__attribute__((address_space(3))) u32*)l, 16, 0, 0);
}

#define WAITVM_(N) asm volatile("s_waitcnt vmcnt(" #N ")" ::: "memory")
#define WAITVM(N) WAITVM_(N)
#define BARF()    do { asm volatile("" ::: "memory"); __builtin_amdgcn_s_barrier(); asm volatile("" ::: "memory"); } while(0)
#define MF(a,b,cc) __builtin_amdgcn_mfma_f32_16x16x32_bf16((a),(b),(cc),0,0,0)

// ---------------- fused cast fp32 -> bf16 for q,k,v ----------------
__global__ __launch_bounds__(256) void cast3_kernel(const float4* __restrict__ q,
                                                    const float4* __restrict__ k,
                                                    const float4* __restrict__ v,
                                                    u16* __restrict__ qo,
                                                    u16* __restrict__ ko,
                                                    u16* __restrict__ vo, int n4){
  const int z = blockIdx.y;
  const float4* in = z==0 ? q : (z==1 ? k : v);
  u16* out = z==0 ? qo : (z==1 ? ko : vo);
  int i = blockIdx.x*256 + threadIdx.x;
  if (i < n4){
    float4 f = in[i];
    union { u16 s[4]; unsigned long long u; } r;
    r.s[0]=f2bf(f.x); r.s[1]=f2bf(f.y); r.s[2]=f2bf(f.z); r.s[3]=f2bf(f.w);
    *(unsigned long long*)(out + (size_t)i*4) = r.u;
  }
}

// ---------------- fused transpose+cast for Wq,Wk,Wv,Wo ----------------
__global__ __launch_bounds__(256) void transpose4_kernel(const float* __restrict__ Wq,
                                                         const float* __restrict__ Wk,
                                                         const float* __restrict__ Wv,
                                                         const float* __restrict__ Wo,
                                                         u16* __restrict__ WqT,
                                                         u16* __restrict__ WkT,
                                                         u16* __restrict__ WvT,
                                                         u16* __restrict__ WoT){
  const int z = blockIdx.z;
  const float* W = z==0?Wq:(z==1?Wk:(z==2?Wv:Wo));
  u16* WT = z==0?WqT:(z==1?WkT:(z==2?WvT:WoT));
  const int N = (z==1||z==2) ? NKV : DIM;
  const int K = DIM;
  int n0 = blockIdx.x*32, k0 = blockIdx.y*32;
  if (n0 >= N) return;
  __shared__ float tile[32][33];
  int tx = threadIdx.x & 31, ty = threadIdx.x >> 5;   // ty 0..7
  #pragma unroll
  for (int i=0;i<4;i++){
    int kk = ty + i*8;
    tile[kk][tx] = W[(size_t)(k0+kk)*N + n0 + tx];
  }
  __syncthreads();
  #pragma unroll
  for (int i=0;i<4;i++){
    int n = ty + i*8;
    WT[(size_t)(n0+n)*K + k0 + tx] = f2bf(tile[tx][n]);
  }
}

// ================= QKV projection: 256x256, BK=64, spread staging (r9 verbatim) =================
__global__ __launch_bounds__(512, 1) void gemm_qkv_kernel(const u16* __restrict__ Aq,
                                                          const u16* __restrict__ Ak,
                                                          const u16* __restrict__ Av,
                                                          const u16* __restrict__ BT,
                                                          const float* __restrict__ bq,
                                                          const float* __restrict__ bk,
                                                          const float* __restrict__ bv,
                                                          u16* __restrict__ Qp,
                                                          u16* __restrict__ Kp,
                                                          u16* __restrict__ Vp){
  __shared__ __align__(16) u16 lds[65536];   // 128KB
  char* ldsb = (char*)lds;
  const int t = threadIdx.x, lane = t & 63, w = t >> 6;
  const int wm = w >> 2, wn = w & 3, g = lane >> 4, c = lane & 15;
  int bid = blockIdx.x;
  bid = (bid & 7)*24 + (bid >> 3);           // 192 = 8*24, bijective
  const int mt = bid / 12, nt = bid - mt*12;
  const int m0 = mt*256, n0 = nt*256;
  const int seg = (n0 >= 2560) ? 2 : (n0 >= 2048 ? 1 : 0);
  const u16* A = seg==0 ? Aq : (seg==1 ? Ak : Av);
  const float* bias = seg==0 ? bq : (seg==1 ? bk : bv);
  const int nbase = seg==0 ? 0 : (seg==1 ? 2048 : 2560);

  const int rA = t >> 3;                                  // 0..63
  const int kc = ((t & 7) ^ (rA & 7)) * 8;                // pre-swizzled source k-chunk
  const u16* gA = A  + (size_t)(m0 + rA)*DIM + kc;
  const u16* gB = BT + (size_t)(n0 + ((rA>>5)<<6) + (rA & 31))*DIM + kc;

  const u32 ko0 = (u32)((g*16) ^ ((c&7)<<4));
  const u32 ko1 = (u32)((64 + g*16) ^ ((c&7)<<4));
  const u32 aoff = wm*8192 + c*128;
  const u32 boff = wn*4096 + c*128;

#define STGA_(PA, KT, ABASE) do{ \
    gload_lds16(gA + (size_t)(KT)*64 + (size_t)((PA)*64)*DIM,       ldsb + (ABASE) + (PA)*16384 + t*16); \
    gload_lds16(gA + (size_t)(KT)*64 + (size_t)((PA)*64+128)*DIM,   ldsb + (ABASE) + (PA)*16384 + 8192 + t*16); }while(0)
#define STGB_(PB, KT, BBASE) do{ \
    gload_lds16(gB + (size_t)(KT)*64 + (size_t)((PB)*32)*DIM,       ldsb + (BBASE) + (PB)*16384 + t*16); \
    gload_lds16(gB + (size_t)(KT)*64 + (size_t)((PB)*32+128)*DIM,   ldsb + (BBASE) + (PB)*16384 + 8192 + t*16); }while(0)
#define LD8(OFF) (*(const short8v*)(ldsb + (OFF)))

  const f32x4 fzero = {0.f,0.f,0.f,0.f};
  f32x4 acc[8][4];
  #pragma unroll
  for (int i=0;i<8;i++)
    #pragma unroll
    for (int j=0;j<4;j++) acc[i][j] = fzero;

#define RD_A(PABASE) do{ _Pragma("unroll") for (int q=0;q<4;q++){ \
    a_[q][0] = LD8((PABASE) + aoff + q*2048 + ko0); \
    a_[q][1] = LD8((PABASE) + aoff + q*2048 + ko1); } }while(0)
#define RD_B(DST, PBBASE) do{ _Pragma("unroll") for (int s=0;s<2;s++){ \
    DST[s][0] = LD8((PBBASE) + boff + s*2048 + ko0); \
    DST[s][1] = LD8((PBBASE) + boff + s*2048 + ko1); } }while(0)

#define MM16(BSRC, FM0, FN0) do{ __builtin_amdgcn_s_setprio(1); \
    _Pragma("unroll") for (int q=0;q<4;q++) \
      _Pragma("unroll") for (int s=0;s<2;s++){ \
        acc[(FM0)+q][(FN0)+s] = MF(a_[q][0], BSRC[s][0], acc[(FM0)+q][(FN0)+s]); \
        acc[(FM0)+q][(FN0)+s] = MF(a_[q][1], BSRC[s][1], acc[(FM0)+q][(FN0)+s]); } \
    __builtin_amdgcn_s_setprio(0); }while(0)

// phases: p0=A0xB0, p1=A0xB1, p2=A1xB1, p3=A1xB0 (B0 kept live).
// stages during tile t (for t+1): p0:A0' p1:B0' p2:B1' p3:A1' (2 loads each).
// fences: vmcnt(4) at p0/p1/p3 closes; none at p2; tail 2/0.
#define QSTEP(TT, CUR, DOSTG, TAIL) do{ \
    const u32 AC = (CUR)*32768,  BC2 = 65536 + (CUR)*32768; \
    const u32 AN = (CUR^1)*32768, BN2 = 65536 + (CUR^1)*32768; \
    short8v a_[4][2], b0_[2][2], b1_[2][2]; \
    /* p0 */ \
    RD_A(AC); RD_B(b0_, BC2); \
    if (DOSTG) STGA_(0, (TT)+1, AN); \
    MM16(b0_, 0, 0); \
    if (TAIL) { WAITVM(2); } else { WAITVM(4); } \
    BARF(); \
    /* p1 */ \
    RD_B(b1_, BC2 + 16384); \
    if (DOSTG) STGB_(0, (TT)+1, BN2); \
    MM16(b1_, 0, 2); \
    if (TAIL) { WAITVM(0); } else { WAITVM(4); } \
    BARF(); \
    /* p2 */ \
    RD_A(AC + 16384); \
    if (DOSTG) STGB_(1, (TT)+1, BN2); \
    MM16(b1_, 4, 2); \
    BARF(); \
    /* p3 */ \
    if (DOSTG) STGA_(1, (TT)+1, AN); \
    MM16(b0_, 4, 0); \
    if (!TAIL) { WAITVM(4); } \
    BARF(); \
  }while(0)

  // prologue: tile 0, order A0,B0,B1,A1 (positions 1-8)
  STGA_(0, 0, 0); STGB_(0, 0, 65536); STGB_(1, 0, 65536); STGA_(1, 0, 0);
  WAITVM(4);
  BARF();

  #pragma unroll 1
  for (int tt = 0; tt < 30; tt += 2){
    QSTEP(tt,   0, 1, 0);
    QSTEP(tt+1, 1, 1, 0);
  }
  QSTEP(30, 0, 1, 0);
  QSTEP(31, 1, 0, 1);
#undef QSTEP

  WAITVM(0);
  __syncthreads();

  // ---- frag-permuted epilogue; Q additionally pre-scaled by QSCL ----
  u16* st = lds + w*8192;
  const float osc = (seg == 0) ? QSCL : 1.0f;
  if (seg == 2){
    #pragma unroll
    for (int fm=0; fm<8; fm++){
      #pragma unroll
      for (int fn=0; fn<4; fn++){
        float bvv = bias[n0 - nbase + wn*64 + fn*16 + c];
        int vbase = (fm>>1)*2048 + fn*512 + (g*16 + c)*8 + (fm&1)*4;
        *(u32*)&st[vbase]     = cvtpk(acc[fm][fn][0]+bvv, acc[fm][fn][1]+bvv);
        *(u32*)&st[vbase + 2] = cvtpk(acc[fm][fn][2]+bvv, acc[fm][fn][3]+bvv);
      }
    }
  } else {
    #pragma unroll
    for (int fm=0; fm<8; fm++){
      #pragma unroll
      for (int fn=0; fn<4; fn++){
        float bvv = bias[n0 - nbase + wn*64 + fn*16 + c];
        int sbase = (fm>>1)*2048 + ((fm&1)*2 + (fn>>1))*512 + (c>>2)*128 + (fn&1)*4 + (c&3);
        #pragma unroll
        for (int r=0; r<4; r++)
          st[sbase + (4*g + r)*8] = f2bf((acc[fm][fn][r] + bvv)*osc);
      }
    }
  }
  __syncthreads();
  {
    const int bb = m0 >> 11;
    const int st0 = ((m0 & 2047) >> 5) + wm*4;
    u16* dst;
    if (seg == 0)      dst = Qp + (((size_t)bb*HQN  + (n0>>6)        + wn) << 17);
    else if (seg == 1) dst = Kp + (((size_t)bb*HKVN + ((n0-2048)>>6) + wn) << 17);
    else               dst = Vp + (((size_t)bb*HKVN + ((n0-2560)>>6) + wn) << 17);
    dst += (size_t)st0*2048;
    #pragma unroll
    for (int i=0;i<16;i++)
      *(short8v*)(dst + lane*8 + i*512) = *(const short8v*)(st + lane*8 + i*512);
  }
#undef STGA_
#undef STGB_
#undef RD_A
#undef RD_B
#undef MM16
#undef LD8
}

// ================= O projection: 256x128, BK=64, 2 phases, spread staging (r9 verbatim) =================
__global__ __launch_bounds__(512, 1) void gemm_o_kernel(const u16* __restrict__ A,
                                                        const u16* __restrict__ BT,
                                                        const float* __restrict__ bias,
                                                        float* __restrict__ C){
  __shared__ __align__(16) u16 lds[49152];   // 96KB
  char* ldsb = (char*)lds;
  const int t = threadIdx.x, lane = t & 63, w = t >> 6;
  const int wm = w >> 2, wn = w & 3, g = lane >> 4, c = lane & 15;
  int bid = blockIdx.x;
  bid = (bid & 7)*32 + (bid >> 3);           // 256 = 8*32
  const int m0 = (bid >> 4)*256, n0 = (bid & 15)*128;

  const int rA = t >> 3;
  const int kc = ((t & 7) ^ (rA & 7)) * 8;
  const u16* gA = A  + (size_t)(m0 + rA)*DIM + kc;
  const u16* gB = BT + (size_t)(n0 + rA)*DIM + kc;

  const u32 ko0 = (u32)((g*16) ^ ((c&7)<<4));
  const u32 ko1 = (u32)((64 + g*16) ^ ((c&7)<<4));
  const u32 aoff = wm*8192 + c*128;
  const u32 boffo = wn*4096 + c*128;

#define STGA_(PA, KT, ABASE) do{ \
    gload_lds16(gA + (size_t)(KT)*64 + (size_t)((PA)*64)*DIM,       ldsb + (ABASE) + (PA)*16384 + t*16); \
    gload_lds16(gA + (size_t)(KT)*64 + (size_t)((PA)*64+128)*DIM,   ldsb + (ABASE) + (PA)*16384 + 8192 + t*16); }while(0)
#define STGB_O(KT, BBASE) do{ \
    gload_lds16(gB + (size_t)(KT)*64,                     ldsb + (BBASE) + t*16); \
    gload_lds16(gB + (size_t)(KT)*64 + (size_t)64*DIM,    ldsb + (BBASE) + 8192 + t*16); }while(0)
#define LD8(OFF) (*(const short8v*)(ldsb + (OFF)))

  const f32x4 fzero = {0.f,0.f,0.f,0.f};
  f32x4 acc[8][2];
  #pragma unroll
  for (int i=0;i<8;i++){ acc[i][0] = fzero; acc[i][1] = fzero; }

#define RD_A(PABASE) do{ _Pragma("unroll") for (int q=0;q<4;q++){ \
    a_[q][0] = LD8((PABASE) + aoff + q*2048 + ko0); \
    a_[q][1] = LD8((PABASE) + aoff + q*2048 + ko1); } }while(0)
#define RD_BO(BBASE) do{ _Pragma("unroll") for (int s=0;s<2;s++){ \
    b_[s][0] = LD8((BBASE) + boffo + s*2048 + ko0); \
    b_[s][1] = LD8((BBASE) + boffo + s*2048 + ko1); } }while(0)

#define MMO(FM0) do{ __builtin_amdgcn_s_setprio(1); \
    _Pragma("unroll") for (int q=0;q<4;q++) \
      _Pragma("unroll") for (int s=0;s<2;s++){ \
        acc[(FM0)+q][s] = MF(a_[q][0], b_[s][0], acc[(FM0)+q][s]); \
        acc[(FM0)+q][s] = MF(a_[q][1], b_[s][1], acc[(FM0)+q][s]); } \
    __builtin_amdgcn_s_setprio(0); }while(0)

// p0: A0xB (B read once, kept); p1: A1xB. stages: p0: A0'+B' (4), p1: A1' (2).
// fences: p0-close vmcnt(4) [steady] / 0 [tail]; p1-close vmcnt(2) [steady].
#define OSTEP(TT, CUR, DOSTG, TAIL) do{ \
    const u32 AC = (CUR)*32768,  BC2 = 65536 + (CUR)*16384; \
    const u32 AN = (CUR^1)*32768, BN2 = 65536 + (CUR^1)*16384; \
    short8v a_[4][2], b_[2][2]; \
    /* p0 */ \
    RD_A(AC); RD_BO(BC2); \
    if (DOSTG) { STGA_(0, (TT)+1, AN); STGB_O((TT)+1, BN2); } \
    MMO(0); \
    if (TAIL) { WAITVM(0); } else { WAITVM(4); } \
    BARF(); \
    /* p1 */ \
    RD_A(AC + 16384); \
    if (DOSTG) STGA_(1, (TT)+1, AN); \
    MMO(4); \
    if (!TAIL) { WAITVM(2); } \
    BARF(); \
  }while(0)

  STGA_(0, 0, 0); STGB_O(0, 65536); STGA_(1, 0, 0);
  WAITVM(2);
  BARF();

  #pragma unroll 1
  for (int tt = 0; tt < 30; tt += 2){
    OSTEP(tt,   0, 1, 0);
    OSTEP(tt+1, 1, 1, 0);
  }
  OSTEP(30, 0, 1, 0);
  OSTEP(31, 1, 0, 1);
#undef OSTEP

  #pragma unroll
  for (int fm=0; fm<8; fm++){
    #pragma unroll
    for (int s=0; s<2; s++){
      int n = n0 + wn*32 + s*16 + c;
      float bvv = bias[n];
      #pragma unroll
      for (int r=0; r<4; r++){
        int m = m0 + wm*128 + fm*16 + 4*g + r;
        C[(size_t)m*DIM + n] = acc[fm][s][r] + bvv;
      }
    }
  }
#undef STGA_
#undef STGB_O
#undef RD_A
#undef RD_BO
#undef MMO
#undef LD8
}

// ---------------- GQA causal flash attention: 8 waves, shared K/V ring ----------------
// Grid 512: block = 512 thr = 8 waves. Waves 0-3 = 4 q-heads of (b,hkv) on q-tile TB=2Tp;
// waves 4-7 = same heads on TB+1. One K/V tile ingest serves 8 wave-computes (2x r9).
// Per-wave body is r9-verbatim (T -> Tw). Staging: t<256 stages K, t>=256 stages V
// -> exactly 1 gload_lds per wave per tile -> constant fence vmcnt(2).
// Tp = (j<16)? j : 47-j so round-robin CU pairs (bid, bid+256) sum to 66 tiles.
__global__ __launch_bounds__(512) void attn_kernel(const u16* __restrict__ Qp,
                                                   const u16* __restrict__ Kp,
                                                   const u16* __restrict__ Vp,
                                                   u16* __restrict__ Aout){
  const int bid = blockIdx.x;
  const int grp = bid & 15;
  const int j   = bid >> 4;                 // 0..31
  const int Tp  = (j < 16) ? j : 47 - j;    // balance pairing
  const int TB  = 2*Tp;
  const int TMAX = TB + 1;
  const int b   = grp >> 3;
  const int hkv = grp & 7;
  const int t = threadIdx.x;
  const int lane = t & 63, w = t >> 6;      // w 0..7
  const int g = lane >> 4, c = lane & 15;
  const int hq = hkv*4 + (w & 3);
  const int Tw = TB + (w >> 2);             // this wave's q-tile

  __shared__ __align__(16) u16 ring[4][2][2048];   // 32KB

  const u16* Kb = Kp + (((size_t)b*HKVN + hkv) << 17);
  const u16* Vb = Vp + (((size_t)b*HKVN + hkv) << 17);
  const u16* Qb = Qp + (((size_t)b*HQN + hq) << 17);
  const f32x4 fzero = {0.f,0.f,0.f,0.f};

  short8v qf[2][2];
  {
    const u16* qs = Qb + (size_t)Tw*2048 + lane*8;
    qf[0][0] = *(const short8v*)(qs);
    qf[0][1] = *(const short8v*)(qs + 512);
    qf[1][0] = *(const short8v*)(qs + 1024);
    qf[1][1] = *(const short8v*)(qs + 1536);
  }
  float l_r[2] = {0.f, 0.f};
  f32x4 o[2][4];
  #pragma unroll
  for (int qi=0; qi<2; qi++)
    #pragma unroll
    for (int f=0; f<4; f++) o[qi][f] = fzero;

  // prologue: tiles min(0..2,TMAX) into slots 0..2; 1 load per thread per slot
  #pragma unroll
  for (int s=0; s<3; s++){
    const int tc = s > TMAX ? TMAX : s;
    if (t < 256) gload_lds16(Kb + (size_t)tc*2048 + t*8,        &ring[s][0][t*8]);
    else         gload_lds16(Vb + (size_t)tc*2048 + (t-256)*8,  &ring[s][1][(t-256)*8]);
  }

  for (int kt = 0; kt <= TMAX; kt += 4){
    #pragma unroll
    for (int s4 = 0; s4 < 4; ++s4){
      const int kt_ = kt + s4;
      if (kt_ > TMAX) break;
      WAITVM(2);
      BARF();
      {
        const int tc = (kt_+3) > TMAX ? TMAX : (kt_+3);
        const int sn = (s4+3) & 3;
        if (t < 256) gload_lds16(Kb + (size_t)tc*2048 + t*8,       &ring[sn][0][t*8]);
        else         gload_lds16(Vb + (size_t)tc*2048 + (t-256)*8, &ring[sn][1][(t-256)*8]);
      }
      if (kt_ <= Tw){
        short8v kf0 = *(const short8v*)&ring[s4][0][lane*8];
        short8v kf1 = *(const short8v*)&ring[s4][0][512 + lane*8];
        short8v kf2 = *(const short8v*)&ring[s4][0][1024 + lane*8];
        short8v kf3 = *(const short8v*)&ring[s4][0][1536 + lane*8];
        short8v vf0 = *(const short8v*)&ring[s4][1][lane*8];
        short8v vf1 = *(const short8v*)&ring[s4][1][512 + lane*8];
        short8v vf2 = *(const short8v*)&ring[s4][1][1024 + lane*8];
        short8v vf3 = *(const short8v*)&ring[s4][1][1536 + lane*8];
        const bool diag = (kt_ == Tw);
        #pragma unroll
        for (int qi=0; qi<2; qi++){
          f32x4 s0 = fzero, s1 = fzero;
          __builtin_amdgcn_s_setprio(1);
          s0 = MF(kf0, qf[qi][0], s0);
          s0 = MF(kf1, qf[qi][1], s0);
          s1 = MF(kf2, qf[qi][0], s1);
          s1 = MF(kf3, qf[qi][1], s1);
          __builtin_amdgcn_s_setprio(0);
          float p0[4], p1[4];
          #pragma unroll
          for (int r=0; r<4; r++){
            p0[r] = __builtin_amdgcn_exp2f(s0[r]);
            p1[r] = __builtin_amdgcn_exp2f(s1[r]);
          }
          if (diag){
            const int qloc = qi*16 + c;
            #pragma unroll
            for (int r=0; r<4; r++){
              if (4*g + r      > qloc) p0[r] = 0.f;
              if (16 + 4*g + r > qloc) p1[r] = 0.f;
            }
          }
          l_r[qi] += (p0[0]+p0[1]) + (p0[2]+p0[3]) + (p1[0]+p1[1]) + (p1[2]+p1[3]);
          union { u32 u[4]; short8v v; } pu;
          pu.u[0] = cvtpk(p0[0], p0[1]);
          pu.u[1] = cvtpk(p0[2], p0[3]);
          pu.u[2] = cvtpk(p1[0], p1[1]);
          pu.u[3] = cvtpk(p1[2], p1[3]);
          __builtin_amdgcn_s_setprio(1);
          o[qi][0] = MF(pu.v, vf0, o[qi][0]);
          o[qi][1] = MF(pu.v, vf1, o[qi][1]);
          o[qi][2] = MF(pu.v, vf2, o[qi][2]);
          o[qi][3] = MF(pu.v, vf3, o[qi][3]);
          __builtin_amdgcn_s_setprio(0);
        }
      }
    }
  }

  #pragma unroll
  for (int qi=0; qi<2; qi++){
    float ls = l_r[qi];
    ls += __shfl_xor(ls, 16);
    ls += __shfl_xor(ls, 32);
    float li = 1.0f / ls;
    float lf[4];
    #pragma unroll
    for (int r=0; r<4; r++) lf[r] = __shfl(li, 4*g + r);
    #pragma unroll
    for (int f=0; f<4; f++){
      #pragma unroll
      for (int r=0; r<4; r++){
        int q = Tw*32 + qi*16 + 4*g + r;
        Aout[((size_t)b*SS + q)*DIM + hq*HD + f*16 + c] = f2bf(o[qi][f][r]*lf[r]);
      }
    }
  }
}

extern "C" void kernel_launch(void* const* d_in, const int* in_sizes, int n_in,
                              void* d_out, int out_size, void* d_ws, size_t ws_size,
                              hipStream_t stream){
  const float* q  = (const float*)d_in[0];
  const float* k  = (const float*)d_in[1];
  const float* v  = (const float*)d_in[2];
  // d_in[3] = mask: pure causal, handled analytically
  const float* Wq = (const float*)d_in[4];
  const float* bq = (const float*)d_in[5];
  const float* Wk = (const float*)d_in[6];
  const float* bk = (const float*)d_in[7];
  const float* Wv = (const float*)d_in[8];
  const float* bv = (const float*)d_in[9];
  const float* Wo = (const float*)d_in[10];
  const float* bo = (const float*)d_in[11];
  float* out = (float*)d_out;

  char* ws = (char*)d_ws;
  u16* q_bf = (u16*)ws; ws += (size_t)MTOT*DIM*2;
  u16* k_bf = (u16*)ws; ws += (size_t)MTOT*DIM*2;
  u16* v_bf = (u16*)ws; ws += (size_t)MTOT*DIM*2;
  u16* WqT  = (u16*)ws; ws += (size_t)DIM*DIM*2;   // WqT|WkT|WvT contiguous = merged BT
  u16* WkT  = (u16*)ws; ws += (size_t)NKV*DIM*2;
  u16* WvT  = (u16*)ws; ws += (size_t)NKV*DIM*2;
  u16* WoT  = (u16*)ws; ws += (size_t)DIM*DIM*2;
  u16* Qp   = (u16*)ws; ws += (size_t)MTOT*DIM*2;
  u16* Kp   = (u16*)ws; ws += (size_t)MTOT*NKV*2;
  u16* Vp   = (u16*)ws; ws += (size_t)MTOT*NKV*2;
  u16* attn = (u16*)ws; ws += (size_t)MTOT*DIM*2;

  const int n4 = MTOT*DIM/4;
  cast3_kernel<<<dim3(n4/256, 3), 256, 0, stream>>>((const float4*)q, (const float4*)k,
                                                    (const float4*)v, q_bf, k_bf, v_bf, n4);
  transpose4_kernel<<<dim3(DIM/32, DIM/32, 4), 256, 0, stream>>>(Wq, Wk, Wv, Wo,
                                                                 WqT, WkT, WvT, WoT);
  gemm_qkv_kernel<<<192, 512, 0, stream>>>(q_bf, k_bf, v_bf, WqT,
                                           bq, bk, bv, Qp, Kp, Vp);
  attn_kernel<<<512, 512, 0, stream>>>(Qp, Kp, Vp, attn);
  gemm_o_kernel<<<256, 512, 0, stream>>>(attn, WoT, bo, out);
}

// Round 17
// 188.338 us; speedup vs baseline: 1.0129x; 1.0129x over previous
//
#include <hip/hip_runtime.h>

typedef unsigned short u16;
typedef unsigned int u32;
typedef __attribute__((ext_vector_type(8))) short short8v;
typedef __attribute__((ext_vector_type(4))) float f32x4;

#define DIM 2048
#define HQN 32
#define HKVN 8
#define HD 64
#define BB 2
#define SS 2048
#define MTOT (BB*SS)
#define NKV (HKVN*HD)
#define QSCL 0.18033688011112042f   // log2(e)/8, folded into Qp

__device__ __forceinline__ u16 f2bf(float f){
  u32 u = __float_as_uint(f);
  u += 0x7FFFu + ((u >> 16) & 1u);
  return (u16)(u >> 16);
}

__device__ __forceinline__ u32 cvtpk(float a, float b){
  u32 r; asm("v_cvt_pk_bf16_f32 %0, %1, %2" : "=v"(r) : "v"(a), "v"(b)); return r;
}

__device__ __forceinline__ void gload_lds16(const void* g, void* l){
  __builtin_amdgcn_global_load_lds((const __attribute__((address_space(1))) u32*)g,
                                   (__attribute__((address_space(3))) u32*)l, 16, 0, 0);
}

#define WAITVM_(N) asm volatile("s_waitcnt vmcnt(" #N ")" ::: "memory")
#define WAITVM(N) WAITVM_(N)
#define BARF()    do { asm volatile("" ::: "memory"); __builtin_amdgcn_s_barrier(); asm volatile("" ::: "memory"); } while(0)
#define MF(a,b,cc) __builtin_amdgcn_mfma_f32_16x16x32_bf16((a),(b),(cc),0,0,0)

// ---------------- fused cast fp32 -> bf16 for q,k,v ----------------
__global__ __launch_bounds__(256) void cast3_kernel(const float4* __restrict__ q,
                                                    const float4* __restrict__ k,
                                                    const float4* __restrict__ v,
                                                    u16* __restrict__ qo,
                                                    u16* __restrict__ ko,
                                                    u16* __restrict__ vo, int n4){
  const int z = blockIdx.y;
  const float4* in = z==0 ? q : (z==1 ? k : v);
  u16* out = z==0 ? qo : (z==1 ? ko : vo);
  int i = blockIdx.x*256 + threadIdx.x;
  if (i < n4){
    float4 f = in[i];
    union { u16 s[4]; unsigned long long u; } r;
    r.s[0]=f2bf(f.x); r.s[1]=f2bf(f.y); r.s[2]=f2bf(f.z); r.s[3]=f2bf(f.w);
    *(unsigned long long*)(out + (size_t)i*4) = r.u;
  }
}

// ---------------- fused transpose+cast for Wq,Wk,Wv,Wo ----------------
__global__ __launch_bounds__(256) void transpose4_kernel(const float* __restrict__ Wq,
                                                         const float* __restrict__ Wk,
                                                         const float* __restrict__ Wv,
                                                         const float* __restrict__ Wo,
                                                         u16* __restrict__ WqT,
                                                         u16* __restrict__ WkT,
                                                         u16* __restrict__ WvT,
                                                         u16* __restrict__ WoT){
  const int z = blockIdx.z;
  const float* W = z==0?Wq:(z==1?Wk:(z==2?Wv:Wo));
  u16* WT = z==0?WqT:(z==1?WkT:(z==2?WvT:WoT));
  const int N = (z==1||z==2) ? NKV : DIM;
  const int K = DIM;
  int n0 = blockIdx.x*32, k0 = blockIdx.y*32;
  if (n0 >= N) return;
  __shared__ float tile[32][33];
  int tx = threadIdx.x & 31, ty = threadIdx.x >> 5;   // ty 0..7
  #pragma unroll
  for (int i=0;i<4;i++){
    int kk = ty + i*8;
    tile[kk][tx] = W[(size_t)(k0+kk)*N + n0 + tx];
  }
  __syncthreads();
  #pragma unroll
  for (int i=0;i<4;i++){
    int n = ty + i*8;
    WT[(size_t)(n0+n)*K + k0 + tx] = f2bf(tile[tx][n]);
  }
}

// ================= QKV projection: 256x256, BK=64 (32 K-tiles), 1 drain+barrier/tile =================
// All fragment reads issue at tile top (whole slot proven landed by the entry drain);
// stages for tile t+1 issue mid-tile and drain a full tile later (~2000cy > 900cy HBM),
// so the entry vmcnt(0) is ~free. Sync: own-drain + barrier publishes gload_lds writes;
// WAR on the other slot cleared by the same barrier (its readers consumed via MFMA).
__global__ __launch_bounds__(512, 1) void gemm_qkv_kernel(const u16* __restrict__ Aq,
                                                          const u16* __restrict__ Ak,
                                                          const u16* __restrict__ Av,
                                                          const u16* __restrict__ BT,
                                                          const float* __restrict__ bq,
                                                          const float* __restrict__ bk,
                                                          const float* __restrict__ bv,
                                                          u16* __restrict__ Qp,
                                                          u16* __restrict__ Kp,
                                                          u16* __restrict__ Vp){
  __shared__ __align__(16) u16 lds[65536];   // 128KB
  char* ldsb = (char*)lds;
  const int t = threadIdx.x, lane = t & 63, w = t >> 6;
  const int wm = w >> 2, wn = w & 3, g = lane >> 4, c = lane & 15;
  int bid = blockIdx.x;
  bid = (bid & 7)*24 + (bid >> 3);           // 192 = 8*24, bijective
  const int mt = bid / 12, nt = bid - mt*12;
  const int m0 = mt*256, n0 = nt*256;
  const int seg = (n0 >= 2560) ? 2 : (n0 >= 2048 ? 1 : 0);
  const u16* A = seg==0 ? Aq : (seg==1 ? Ak : Av);
  const float* bias = seg==0 ? bq : (seg==1 ? bk : bv);
  const int nbase = seg==0 ? 0 : (seg==1 ? 2048 : 2560);

  const int rA = t >> 3;                                  // 0..63
  const int kc = ((t & 7) ^ (rA & 7)) * 8;                // pre-swizzled source k-chunk
  const u16* gA = A  + (size_t)(m0 + rA)*DIM + kc;
  const u16* gB = BT + (size_t)(n0 + ((rA>>5)<<6) + (rA & 31))*DIM + kc;

  const u32 ko0 = (u32)((g*16) ^ ((c&7)<<4));
  const u32 ko1 = (u32)((64 + g*16) ^ ((c&7)<<4));
  const u32 aoff = wm*8192 + c*128;
  const u32 boff = wn*4096 + c*128;

#define STGA_(PA, KT, ABASE) do{ \
    gload_lds16(gA + (size_t)(KT)*64 + (size_t)((PA)*64)*DIM,       ldsb + (ABASE) + (PA)*16384 + t*16); \
    gload_lds16(gA + (size_t)(KT)*64 + (size_t)((PA)*64+128)*DIM,   ldsb + (ABASE) + (PA)*16384 + 8192 + t*16); }while(0)
#define STGB_(PB, KT, BBASE) do{ \
    gload_lds16(gB + (size_t)(KT)*64 + (size_t)((PB)*32)*DIM,       ldsb + (BBASE) + (PB)*16384 + t*16); \
    gload_lds16(gB + (size_t)(KT)*64 + (size_t)((PB)*32+128)*DIM,   ldsb + (BBASE) + (PB)*16384 + 8192 + t*16); }while(0)
#define LD8(OFF) (*(const short8v*)(ldsb + (OFF)))

  const f32x4 fzero = {0.f,0.f,0.f,0.f};
  f32x4 acc[8][4];
  #pragma unroll
  for (int i=0;i<8;i++)
    #pragma unroll
    for (int j=0;j<4;j++) acc[i][j] = fzero;

#define RD_A(DST, PABASE) do{ _Pragma("unroll") for (int q=0;q<4;q++){ \
    DST[q][0] = LD8((PABASE) + aoff + q*2048 + ko0); \
    DST[q][1] = LD8((PABASE) + aoff + q*2048 + ko1); } }while(0)
#define RD_B(DST, PBBASE) do{ _Pragma("unroll") for (int s=0;s<2;s++){ \
    DST[s][0] = LD8((PBBASE) + boff + s*2048 + ko0); \
    DST[s][1] = LD8((PBBASE) + boff + s*2048 + ko1); } }while(0)

#define MM16(ASRC, BSRC, FM0, FN0) do{ __builtin_amdgcn_s_setprio(1); \
    _Pragma("unroll") for (int q=0;q<4;q++) \
      _Pragma("unroll") for (int s=0;s<2;s++){ \
        acc[(FM0)+q][(FN0)+s] = MF(ASRC[q][0], BSRC[s][0], acc[(FM0)+q][(FN0)+s]); \
        acc[(FM0)+q][(FN0)+s] = MF(ASRC[q][1], BSRC[s][1], acc[(FM0)+q][(FN0)+s]); } \
    __builtin_amdgcn_s_setprio(0); }while(0)

// One K-tile: drain+barrier, read a0/b0/b1, issue all 8 stages, read a1, 4 MFMA clusters.
#define QSTEP(TT, CUR, DOSTG) do{ \
    const u32 AC = (CUR)*32768,  BC2 = 65536 + (CUR)*32768; \
    const u32 AN = (CUR^1)*32768, BN2 = 65536 + (CUR^1)*32768; \
    short8v a0_[4][2], a1_[4][2], b0_[2][2], b1_[2][2]; \
    WAITVM(0); \
    BARF(); \
    RD_A(a0_, AC); RD_B(b0_, BC2); RD_B(b1_, BC2 + 16384); \
    if (DOSTG){ STGA_(0, (TT)+1, AN); STGB_(0, (TT)+1, BN2); \
                STGB_(1, (TT)+1, BN2); STGA_(1, (TT)+1, AN); } \
    RD_A(a1_, AC + 16384); \
    MM16(a0_, b0_, 0, 0); \
    MM16(a0_, b1_, 0, 2); \
    MM16(a1_, b1_, 4, 2); \
    MM16(a1_, b0_, 4, 0); \
  }while(0)

  // prologue: stage tile 0 (8 loads); loop-entry drain covers it.
  STGA_(0, 0, 0); STGB_(0, 0, 65536); STGB_(1, 0, 65536); STGA_(1, 0, 0);

  // 32 K-tiles total (DIM/BK = 2048/64). Tile 31 staged by tile 30; no stage at tail.
  #pragma unroll 1
  for (int tt = 0; tt < 30; tt += 2){
    QSTEP(tt,   0, 1);
    QSTEP(tt+1, 1, 1);
  }
  QSTEP(30, 0, 1);
  QSTEP(31, 1, 0);
#undef QSTEP

  __syncthreads();   // all waves done reading lds (no stages outstanding)

  // ---- frag-permuted epilogue; Q additionally pre-scaled by QSCL ----
  u16* st = lds + w*8192;
  const float osc = (seg == 0) ? QSCL : 1.0f;
  if (seg == 2){
    #pragma unroll
    for (int fm=0; fm<8; fm++){
      #pragma unroll
      for (int fn=0; fn<4; fn++){
        float bvv = bias[n0 - nbase + wn*64 + fn*16 + c];
        int vbase = (fm>>1)*2048 + fn*512 + (g*16 + c)*8 + (fm&1)*4;
        *(u32*)&st[vbase]     = cvtpk(acc[fm][fn][0]+bvv, acc[fm][fn][1]+bvv);
        *(u32*)&st[vbase + 2] = cvtpk(acc[fm][fn][2]+bvv, acc[fm][fn][3]+bvv);
      }
    }
  } else {
    #pragma unroll
    for (int fm=0; fm<8; fm++){
      #pragma unroll
      for (int fn=0; fn<4; fn++){
        float bvv = bias[n0 - nbase + wn*64 + fn*16 + c];
        int sbase = (fm>>1)*2048 + ((fm&1)*2 + (fn>>1))*512 + (c>>2)*128 + (fn&1)*4 + (c&3);
        #pragma unroll
        for (int r=0; r<4; r++)
          st[sbase + (4*g + r)*8] = f2bf((acc[fm][fn][r] + bvv)*osc);
      }
    }
  }
  __syncthreads();
  {
    const int bb = m0 >> 11;
    const int st0 = ((m0 & 2047) >> 5) + wm*4;
    u16* dst;
    if (seg == 0)      dst = Qp + (((size_t)bb*HQN  + (n0>>6)        + wn) << 17);
    else if (seg == 1) dst = Kp + (((size_t)bb*HKVN + ((n0-2048)>>6) + wn) << 17);
    else               dst = Vp + (((size_t)bb*HKVN + ((n0-2560)>>6) + wn) << 17);
    dst += (size_t)st0*2048;
    #pragma unroll
    for (int i=0;i<16;i++)
      *(short8v*)(dst + lane*8 + i*512) = *(const short8v*)(st + lane*8 + i*512);
  }
#undef STGA_
#undef STGB_
#undef RD_A
#undef RD_B
#undef MM16
#undef LD8
}

// ================= O projection: 256x128, BK=64 (32 K-tiles), 1 drain+barrier/tile =================
__global__ __launch_bounds__(512, 1) void gemm_o_kernel(const u16* __restrict__ A,
                                                        const u16* __restrict__ BT,
                                                        const float* __restrict__ bias,
                                                        float* __restrict__ C){
  __shared__ __align__(16) u16 lds[49152];   // 96KB
  char* ldsb = (char*)lds;
  const int t = threadIdx.x, lane = t & 63, w = t >> 6;
  const int wm = w >> 2, wn = w & 3, g = lane >> 4, c = lane & 15;
  int bid = blockIdx.x;
  bid = (bid & 7)*32 + (bid >> 3);           // 256 = 8*32
  const int m0 = (bid >> 4)*256, n0 = (bid & 15)*128;

  const int rA = t >> 3;
  const int kc = ((t & 7) ^ (rA & 7)) * 8;
  const u16* gA = A  + (size_t)(m0 + rA)*DIM + kc;
  const u16* gB = BT + (size_t)(n0 + rA)*DIM + kc;

  const u32 ko0 = (u32)((g*16) ^ ((c&7)<<4));
  const u32 ko1 = (u32)((64 + g*16) ^ ((c&7)<<4));
  const u32 aoff = wm*8192 + c*128;
  const u32 boffo = wn*4096 + c*128;

#define STGA_(PA, KT, ABASE) do{ \
    gload_lds16(gA + (size_t)(KT)*64 + (size_t)((PA)*64)*DIM,       ldsb + (ABASE) + (PA)*16384 + t*16); \
    gload_lds16(gA + (size_t)(KT)*64 + (size_t)((PA)*64+128)*DIM,   ldsb + (ABASE) + (PA)*16384 + 8192 + t*16); }while(0)
#define STGB_O(KT, BBASE) do{ \
    gload_lds16(gB + (size_t)(KT)*64,                     ldsb + (BBASE) + t*16); \
    gload_lds16(gB + (size_t)(KT)*64 + (size_t)64*DIM,    ldsb + (BBASE) + 8192 + t*16); }while(0)
#define LD8(OFF) (*(const short8v*)(ldsb + (OFF)))

  const f32x4 fzero = {0.f,0.f,0.f,0.f};
  f32x4 acc[8][2];
  #pragma unroll
  for (int i=0;i<8;i++){ acc[i][0] = fzero; acc[i][1] = fzero; }

#define RD_A(DST, PABASE) do{ _Pragma("unroll") for (int q=0;q<4;q++){ \
    DST[q][0] = LD8((PABASE) + aoff + q*2048 + ko0); \
    DST[q][1] = LD8((PABASE) + aoff + q*2048 + ko1); } }while(0)
#define RD_BO(DST, BBASE) do{ _Pragma("unroll") for (int s=0;s<2;s++){ \
    DST[s][0] = LD8((BBASE) + boffo + s*2048 + ko0); \
    DST[s][1] = LD8((BBASE) + boffo + s*2048 + ko1); } }while(0)

#define MMO(ASRC, FM0) do{ __builtin_amdgcn_s_setprio(1); \
    _Pragma("unroll") for (int q=0;q<4;q++) \
      _Pragma("unroll") for (int s=0;s<2;s++){ \
        acc[(FM0)+q][s] = MF(ASRC[q][0], b_[s][0], acc[(FM0)+q][s]); \
        acc[(FM0)+q][s] = MF(ASRC[q][1], b_[s][1], acc[(FM0)+q][s]); } \
    __builtin_amdgcn_s_setprio(0); }while(0)

#define OSTEP(TT, CUR, DOSTG) do{ \
    const u32 AC = (CUR)*32768,  BC2 = 65536 + (CUR)*16384; \
    const u32 AN = (CUR^1)*32768, BN2 = 65536 + (CUR^1)*16384; \
    short8v a0_[4][2], a1_[4][2], b_[2][2]; \
    WAITVM(0); \
    BARF(); \
    RD_A(a0_, AC); RD_BO(b_, BC2); \
    if (DOSTG){ STGA_(0, (TT)+1, AN); STGB_O((TT)+1, BN2); STGA_(1, (TT)+1, AN); } \
    RD_A(a1_, AC + 16384); \
    MMO(a0_, 0); \
    MMO(a1_, 4); \
  }while(0)

  STGA_(0, 0, 0); STGB_O(0, 65536); STGA_(1, 0, 0);

  // 32 K-tiles total.
  #pragma unroll 1
  for (int tt = 0; tt < 30; tt += 2){
    OSTEP(tt,   0, 1);
    OSTEP(tt+1, 1, 1);
  }
  OSTEP(30, 0, 1);
  OSTEP(31, 1, 0);
#undef OSTEP

  #pragma unroll
  for (int fm=0; fm<8; fm++){
    #pragma unroll
    for (int s=0; s<2; s++){
      int n = n0 + wn*32 + s*16 + c;
      float bvv = bias[n];
      #pragma unroll
      for (int r=0; r<4; r++){
        int m = m0 + wm*128 + fm*16 + 4*g + r;
        C[(size_t)m*DIM + n] = acc[fm][s][r] + bvv;
      }
    }
  }
#undef STGA_
#undef STGB_O
#undef RD_A
#undef RD_BO
#undef MMO
#undef LD8
}

// ---------------- GQA causal flash attention (r14/r9-exact, verified passing) ----------------
__global__ __launch_bounds__(256) void attn_kernel(const u16* __restrict__ Qp,
                                                   const u16* __restrict__ Kp,
                                                   const u16* __restrict__ Vp,
                                                   u16* __restrict__ Aout){
  const int bid = blockIdx.x;
  const int grp = bid & 15;
  const int T   = 63 - (bid >> 4);     // heavy blocks dispatch first
  const int b   = grp >> 3;
  const int hkv = grp & 7;
  const int t = threadIdx.x;
  const int lane = t & 63, w = t >> 6;
  const int g = lane >> 4, c = lane & 15;
  const int hq = hkv*4 + w;

  __shared__ __align__(16) u16 ring[4][2][2048];   // 32KB

  const u16* Kb = Kp + (((size_t)b*HKVN + hkv) << 17);
  const u16* Vb = Vp + (((size_t)b*HKVN + hkv) << 17);
  const u16* Qb = Qp + (((size_t)b*HQN + hq) << 17);
  const f32x4 fzero = {0.f,0.f,0.f,0.f};

  short8v qf[2][2];
  {
    const u16* qs = Qb + (size_t)T*2048 + lane*8;
    qf[0][0] = *(const short8v*)(qs);
    qf[0][1] = *(const short8v*)(qs + 512);
    qf[1][0] = *(const short8v*)(qs + 1024);
    qf[1][1] = *(const short8v*)(qs + 1536);
  }
  float l_r[2] = {0.f, 0.f};
  f32x4 o[2][4];
  #pragma unroll
  for (int qi=0; qi<2; qi++)
    #pragma unroll
    for (int f=0; f<4; f++) o[qi][f] = fzero;

  #pragma unroll
  for (int s=0; s<3; s++){
    const int tc = s > T ? T : s;
    gload_lds16(Kb + (size_t)tc*2048 + t*8, &ring[s][0][t*8]);
    gload_lds16(Vb + (size_t)tc*2048 + t*8, &ring[s][1][t*8]);
  }

  for (int kt = 0; kt <= T; kt += 4){
    #pragma unroll
    for (int s4 = 0; s4 < 4; ++s4){
      const int kt_ = kt + s4;
      if (kt_ > T) break;
      WAITVM(4);
      BARF();
      short8v kf0 = *(const short8v*)&ring[s4][0][lane*8];
      short8v kf1 = *(const short8v*)&ring[s4][0][512 + lane*8];
      short8v kf2 = *(const short8v*)&ring[s4][0][1024 + lane*8];
      short8v kf3 = *(const short8v*)&ring[s4][0][1536 + lane*8];
      short8v vf0 = *(const short8v*)&ring[s4][1][lane*8];
      short8v vf1 = *(const short8v*)&ring[s4][1][512 + lane*8];
      short8v vf2 = *(const short8v*)&ring[s4][1][1024 + lane*8];
      short8v vf3 = *(const short8v*)&ring[s4][1][1536 + lane*8];
      {
        const int tc = (kt_+3) > T ? T : (kt_+3);
        const int sn = (s4+3) & 3;
        gload_lds16(Kb + (size_t)tc*2048 + t*8, &ring[sn][0][t*8]);
        gload_lds16(Vb + (size_t)tc*2048 + t*8, &ring[sn][1][t*8]);
      }
      const bool diag = (kt_ == T);
      #pragma unroll
      for (int qi=0; qi<2; qi++){
        f32x4 s0 = fzero, s1 = fzero;
        __builtin_amdgcn_s_setprio(1);
        s0 = MF(kf0, qf[qi][0], s0);
        s0 = MF(kf1, qf[qi][1], s0);
        s1 = MF(kf2, qf[qi][0], s1);
        s1 = MF(kf3, qf[qi][1], s1);
        __builtin_amdgcn_s_setprio(0);
        float p0[4], p1[4];
        #pragma unroll
        for (int r=0; r<4; r++){
          p0[r] = __builtin_amdgcn_exp2f(s0[r]);
          p1[r] = __builtin_amdgcn_exp2f(s1[r]);
        }
        if (diag){
          const int qloc = qi*16 + c;
          #pragma unroll
          for (int r=0; r<4; r++){
            if (4*g + r      > qloc) p0[r] = 0.f;
            if (16 + 4*g + r > qloc) p1[r] = 0.f;
          }
        }
        l_r[qi] += (p0[0]+p0[1]) + (p0[2]+p0[3]) + (p1[0]+p1[1]) + (p1[2]+p1[3]);
        union { u32 u[4]; short8v v; } pu;
        pu.u[0] = cvtpk(p0[0], p0[1]);
        pu.u[1] = cvtpk(p0[2], p0[3]);
        pu.u[2] = cvtpk(p1[0], p1[1]);
        pu.u[3] = cvtpk(p1[2], p1[3]);
        __builtin_amdgcn_s_setprio(1);
        o[qi][0] = MF(pu.v, vf0, o[qi][0]);
        o[qi][1] = MF(pu.v, vf1, o[qi][1]);
        o[qi][2] = MF(pu.v, vf2, o[qi][2]);
        o[qi][3] = MF(pu.v, vf3, o[qi][3]);
        __builtin_amdgcn_s_setprio(0);
      }
    }
  }

  #pragma unroll
  for (int qi=0; qi<2; qi++){
    float ls = l_r[qi];
    ls += __shfl_xor(ls, 16);
    ls += __shfl_xor(ls, 32);
    float li = 1.0f / ls;
    float lf[4];
    #pragma unroll
    for (int r=0; r<4; r++) lf[r] = __shfl(li, 4*g + r);
    #pragma unroll
    for (int f=0; f<4; f++){
      #pragma unroll
      for (int r=0; r<4; r++){
        int q = T*32 + qi*16 + 4*g + r;
        Aout[((size_t)b*SS + q)*DIM + hq*HD + f*16 + c] = f2bf(o[qi][f][r]*lf[r]);
      }
    }
  }
}

extern "C" void kernel_launch(void* const* d_in, const int* in_sizes, int n_in,
                              void* d_out, int out_size, void* d_ws, size_t ws_size,
                              hipStream_t stream){
  const float* q  = (const float*)d_in[0];
  const float* k  = (const float*)d_in[1];
  const float* v  = (const float*)d_in[2];
  // d_in[3] = mask: pure causal, handled analytically
  const float* Wq = (const float*)d_in[4];
  const float* bq = (const float*)d_in[5];
  const float* Wk = (const float*)d_in[6];
  const float* bk = (const float*)d_in[7];
  const float* Wv = (const float*)d_in[8];
  const float* bv = (const float*)d_in[9];
  const float* Wo = (const float*)d_in[10];
  const float* bo = (const float*)d_in[11];
  float* out = (float*)d_out;

  char* ws = (char*)d_ws;
  u16* q_bf = (u16*)ws; ws += (size_t)MTOT*DIM*2;
  u16* k_bf = (u16*)ws; ws += (size_t)MTOT*DIM*2;
  u16* v_bf = (u16*)ws; ws += (size_t)MTOT*DIM*2;
  u16* WqT  = (u16*)ws; ws += (size_t)DIM*DIM*2;   // WqT|WkT|WvT contiguous = merged BT
  u16* WkT  = (u16*)ws; ws += (size_t)NKV*DIM*2;
  u16* WvT  = (u16*)ws; ws += (size_t)NKV*DIM*2;
  u16* WoT  = (u16*)ws; ws += (size_t)DIM*DIM*2;
  u16* Qp   = (u16*)ws; ws += (size_t)MTOT*DIM*2;
  u16* Kp   = (u16*)ws; ws += (size_t)MTOT*NKV*2;
  u16* Vp   = (u16*)ws; ws += (size_t)MTOT*NKV*2;
  u16* attn = (u16*)ws; ws += (size_t)MTOT*DIM*2;

  const int n4 = MTOT*DIM/4;
  cast3_kernel<<<dim3(n4/256, 3), 256, 0, stream>>>((const float4*)q, (const float4*)k,
                                                    (const float4*)v, q_bf, k_bf, v_bf, n4);
  transpose4_kernel<<<dim3(DIM/32, DIM/32, 4), 256, 0, stream>>>(Wq, Wk, Wv, Wo,
                                                                 WqT, WkT, WvT, WoT);
  gemm_qkv_kernel<<<192, 512, 0, stream>>>(q_bf, k_bf, v_bf, WqT,
                                           bq, bk, bv, Qp, Kp, Vp);
  attn_kernel<<<1024, 256, 0, stream>>>(Qp, Kp, Vp, attn);
  gemm_o_kernel<<<256, 512, 0, stream>>>(attn, WoT, bo, out);
}